// Round 4
// baseline (257.475 us; speedup 1.0000x reference)
//
#include <hip/hip_runtime.h>

// StrokeField R10: 3-stage zero-move pipelined blend (1 readlane + 2 uniform
// ds_read_b128 per stroke) + 5-dispatch pipeline with zero memsets.
// R9 post-mortem: 8 readlanes/stroke raised VALUBusy 43->61% with NO time
// gain -- readlanes are VALU instrs; traded 2 LDS ops for 8 ALU ops.
// R10 kF: per stroke issue sid=readlane(myId,c) then TWO uniform-address
// ds_read_b128 (broadcast, conflict-free), software-pipelined depth 2 via
// unroll-by-3 rotation (no register moves): load c-3 after computing c,
// ~120cy of compute covers ds_read latency. 29 VALU + 1 rl + 2 ds = ~33.
// Pipeline: kA writes per-block count vectors (no atomics/memset); kB
// reduces+scans; kD 8 segments/supercell (512 blocks, blockIdx%8==s%8 keeps
// XCD pinning) and writes chunkInfo tails (-1) so the 0xFF memset dies.

#define NC_DIM 16
#define NC (NC_DIM * NC_DIM * NC_DIM)
#define MAXS 512
#define CELL_INV 8.0f
#define CHK 128

typedef unsigned char u8;
typedef unsigned short u16;
typedef unsigned long long u64;

__device__ __forceinline__ void contract_pt(float x, float y, float z,
                                            float& cx, float& cy, float& cz) {
    float n2 = fmaf(x, x, fmaf(y, y, z * z));
    float nn = fmaxf(__builtin_amdgcn_sqrtf(n2), 1e-9f);
    float invn = 1.0f / nn;
    float scl = (nn <= 1.0f) ? 0.5f : (2.0f - invn) * (0.5f * invn);
    cx = x * scl; cy = y * scl; cz = z * scl;
}

__device__ __forceinline__ int cid_of(float cx, float cy, float cz) {
    int ix = (int)floorf((cx + 1.0f) * CELL_INV);
    int iy = (int)floorf((cy + 1.0f) * CELL_INV);
    int iz = (int)floorf((cz + 1.0f) * CELL_INV);
    ix = min(max(ix, 0), 15); iy = min(max(iy, 0), 15); iz = min(max(iz, 0), 15);
    return ix | (iy << 4) | (iz << 8);
}
__device__ __forceinline__ int sid_of(int cid) {
    return ((cid >> 2) & 3) | (((cid >> 6) & 3) << 2) | (((cid >> 10) & 3) << 4);
}
__device__ __forceinline__ int sub_of(int cid) {
    return (cid & 3) | (((cid >> 4) & 3) << 2) | (((cid >> 8) & 3) << 4);
}
__device__ __forceinline__ int cid_from(int s, int t) {
    int ix = (((s) & 3) << 2) | (t & 3);
    int iy = (((s >> 2) & 3) << 2) | ((t >> 2) & 3);
    int iz = (((s >> 4) & 3) << 2) | ((t >> 4) & 3);
    return ix | (iy << 4) | (iz << 8);
}

// KA: contract, write cw, per-block supercell count vector (no atomics).
__global__ __launch_bounds__(256) void kA(
    const float* __restrict__ coords, float* __restrict__ out,
    int* __restrict__ superCntB, int n)
{
    __shared__ int h[64];
    if (threadIdx.x < 64) h[threadIdx.x] = 0;
    __syncthreads();
    float* cw = out + 4 * (size_t)n;
    int base = blockIdx.x * 2048 + threadIdx.x;
#pragma unroll
    for (int k = 0; k < 8; ++k) {
        int i = base + k * 256;
        if (i < n) {
            float cx, cy, cz;
            contract_pt(coords[3 * i], coords[3 * i + 1], coords[3 * i + 2], cx, cy, cz);
            cw[3 * i] = cx; cw[3 * i + 1] = cy; cw[3 * i + 2] = cz;
            atomicAdd(&h[sid_of(cid_of(cx, cy, cz))], 1);
        }
    }
    __syncthreads();
    if (threadIdx.x < 64)
        superCntB[blockIdx.x * 64 + threadIdx.x] = h[threadIdx.x];
}

// KB: reduce per-block count matrix + three 64-wide shuffle scans.
__global__ __launch_bounds__(256) void kB(
    const int* __restrict__ superCntB, int nb,
    int* __restrict__ superCnt, int* __restrict__ superBase,
    int* __restrict__ superCur, int* __restrict__ superSlotBase,
    int* __restrict__ superChunkBase)
{
    __shared__ int part[4][64];
    int t = threadIdx.x, row = t >> 6, lane = t & 63;
    int acc = 0;
    for (int b = row; b < nb; b += 4) acc += superCntB[b * 64 + lane];
    part[row][lane] = acc;
    __syncthreads();
    if (t < 64) {
        int cnt = part[0][t] + part[1][t] + part[2][t] + part[3][t];
        int e = cnt;
        int sc = cnt + 64 * CHK;
        int ch = ((cnt + CHK - 1) >> 7) + 65;
        int ve = e, vs = sc, vc = ch;
        for (int off = 1; off < 64; off <<= 1) {
            int ue = __shfl_up(ve, off, 64);
            int us = __shfl_up(vs, off, 64);
            int uc = __shfl_up(vc, off, 64);
            if (t >= off) { ve += ue; vs += us; vc += uc; }
        }
        superCnt[t] = cnt;
        superBase[t] = ve - e;
        superCur[t] = ve - e;
        superSlotBase[t] = vs - sc;
        superChunkBase[t] = vc - ch;
    }
}

// KC: block-aggregated scatter of float4(cw, idx|sub<<21) + u8 key into
// supercell element runs. sortedTmp aliases out[0..4n).
__global__ __launch_bounds__(256) void kC(
    const float* __restrict__ out, int* __restrict__ superCur,
    float4* __restrict__ sortedTmp, u8* __restrict__ keyArr, int n)
{
    __shared__ int scnt[64], sbase[64];
    if (threadIdx.x < 64) scnt[threadIdx.x] = 0;
    __syncthreads();
    const float* cw = out + 4 * (size_t)n;
    int base = blockIdx.x * 2048 + threadIdx.x;
    float cx[8], cy[8], cz[8];
    int sub[8], sid[8];
#pragma unroll
    for (int k = 0; k < 8; ++k) {
        int i = base + k * 256;
        if (i < n) {
            cx[k] = cw[3 * i]; cy[k] = cw[3 * i + 1]; cz[k] = cw[3 * i + 2];
            int c = cid_of(cx[k], cy[k], cz[k]);
            sub[k] = sub_of(c); sid[k] = sid_of(c);
            atomicAdd(&scnt[sid[k]], 1);
        } else sid[k] = -1;
    }
    __syncthreads();
    if (threadIdx.x < 64) {
        int c = scnt[threadIdx.x];
        sbase[threadIdx.x] = c ? atomicAdd(&superCur[threadIdx.x], c) : 0;
        scnt[threadIdx.x] = 0;
    }
    __syncthreads();
#pragma unroll
    for (int k = 0; k < 8; ++k) {
        if (sid[k] >= 0) {
            int i = base + k * 256;
            int r = atomicAdd(&scnt[sid[k]], 1);
            int slot = sbase[sid[k]] + r;
            sortedTmp[slot] = make_float4(cx[k], cy[k], cz[k],
                                          __int_as_float(i | (sub[k] << 21)));
            keyArr[slot] = (u8)sub[k];
        }
    }
}

// KD: 8 segments per supercell (blockIdx = g*64+s, blockIdx%8==s%8 -> XCD
// pinned). Full-supercell key hist split by segment -> deterministic bases;
// g==0 emits chunkInfo incl. -1 tails (no memset); scatter own segment.
__global__ __launch_bounds__(1024) void kD(
    const int* __restrict__ superCnt, const int* __restrict__ superBase,
    const int* __restrict__ superSlotBase, const int* __restrict__ superChunkBase,
    const float4* __restrict__ sortedTmp, const u8* __restrict__ keyArr,
    float4* __restrict__ sortedPts, int2* __restrict__ chunkInfo, int maxChunks)
{
    __shared__ int hist[8][64];
    __shared__ int cur[64];
    int s = blockIdx.x & 63, g = blockIdx.x >> 6;
    int t = threadIdx.x;
    if (t < 512) ((int*)hist)[t] = 0;
    __syncthreads();
    int cnt = superCnt[s];
    int rb = superBase[s];
    long long c64 = cnt;
    int qb1 = (int)((c64 * 1) >> 3), qb2 = (int)((c64 * 2) >> 3);
    int qb3 = (int)((c64 * 3) >> 3), qb4 = (int)((c64 * 4) >> 3);
    int qb5 = (int)((c64 * 5) >> 3), qb6 = (int)((c64 * 6) >> 3);
    int qb7 = (int)((c64 * 7) >> 3);
    for (int j = t; j < cnt; j += 1024) {
        int sub = keyArr[rb + j];
        int seg = (j >= qb4)
            ? ((j >= qb6) ? ((j >= qb7) ? 7 : 6) : ((j >= qb5) ? 5 : 4))
            : ((j >= qb2) ? ((j >= qb3) ? 3 : 2) : ((j >= qb1) ? 1 : 0));
        atomicAdd(&hist[seg][sub], 1);
    }
    __syncthreads();
    if (t < 64) {
        int c = 0;
#pragma unroll
        for (int gg = 0; gg < 8; ++gg) c += hist[gg][t];
        int slotsz = ((c + CHK - 1) >> 7) << 7;
        int nch = (c + CHK - 1) >> 7;
        int vs = slotsz, vc = nch;
        for (int off = 1; off < 64; off <<= 1) {
            int us = __shfl_up(vs, off, 64);
            int uc = __shfl_up(vc, off, 64);
            if (t >= off) { vs += us; vc += uc; }
        }
        int cellSlot = superSlotBase[s] + (vs - slotsz);
        if (g == 0) {
            int cb0 = superChunkBase[s];
            int cb = cb0 + (vc - nch);
            int cid = cid_from(s, t);
            for (int q = 0; q < nch; ++q) {
                int rem = c - (q << 7); rem = rem > CHK ? CHK : rem;
                chunkInfo[cb + q] = make_int2(cid | (rem << 16), cellSlot + (q << 7));
            }
            int used = __shfl(vc, 63, 64);
            int cap = ((cnt + CHK - 1) >> 7) + 65;
            if (s == 63) cap = maxChunks - cb0;
            for (int q = used + t; q < cap; q += 64)
                chunkInfo[cb0 + q] = make_int2(-1, 0);
        }
        int pre = 0;
        for (int gg = 0; gg < g; ++gg) pre += hist[gg][t];
        cur[t] = cellSlot + pre;
    }
    __syncthreads();
    int q0s[9] = {0, qb1, qb2, qb3, qb4, qb5, qb6, qb7, cnt};
    int j0 = q0s[g], j1 = q0s[g + 1];
    for (int j = j0 + t; j < j1; j += 1024) {
        float4 p = sortedTmp[rb + j];
        int bits = __float_as_int(p.w);
        int sub = (bits >> 21) & 63;
        int r = atomicAdd(&cur[sub], 1);
        p.w = __int_as_float(bits & 0x1FFFFF);
        sortedPts[r] = p;
    }
}

// KF: one wave per 128-pt chunk (2 pts/lane). On-the-fly list build, then
// 3-stage pipelined blend: 1 readlane + 2 uniform ds_read_b128 per stroke.
__global__ __launch_bounds__(256) void kF(
    const float* __restrict__ shape, const float* __restrict__ color,
    const float* __restrict__ alpha,
    const int2* __restrict__ chunkInfo, const float4* __restrict__ sortedPts,
    float* __restrict__ out, int n, int ns, int maxChunks)
{
    __shared__ float4 sA[MAXS];      // (ax, ay, az, K = 0.5 - 5r)
    __shared__ float4 sB[MAXS];      // (dp, cr, cg, cb)
    __shared__ u16 wl[4][MAXS];
    for (int s = threadIdx.x; s < ns; s += blockDim.x) {
        float4 sp = ((const float4*)shape)[s];
        sA[s] = make_float4(sp.x, sp.y, sp.z, fmaf(-5.0f, sp.w, 0.5f));
        sB[s] = make_float4(fmaxf(alpha[s], 0.0f) * 50.0f,
                            color[3 * s], color[3 * s + 1], color[3 * s + 2]);
    }
    __syncthreads();

    int w = threadIdx.x >> 6, lane = threadIdx.x & 63;
    int k = blockIdx.x * 4 + w;
    if (k >= maxChunks) return;
    int2 info = chunkInfo[k];
    if (info.x < 0) return;
    int cell = info.x & 0xFFF;
    int cnum = info.x >> 16;

    float4 pA = sortedPts[info.y + lane];
    float4 pB = sortedPts[info.y + 64 + lane];
    bool vA = lane < cnum;
    bool vB = lane + 64 < cnum;
    int iA = __float_as_int(pA.w) & 0x1FFFFF;
    int iB = __float_as_int(pB.w) & 0x1FFFFF;
    float xA = vA ? pA.x : 1e9f, yA = vA ? pA.y : 1e9f, zA = vA ? pA.z : 1e9f;
    float xB = vB ? pB.x : 1e9f, yB = vB ? pB.y : 1e9f, zB = vB ? pB.z : 1e9f;

    // Build this cell's ordered stroke sublist.
    int ix = cell & 15, iy = (cell >> 4) & 15, iz = cell >> 8;
    float lox = -1.0f + ix * 0.125f, hix = lox + 0.125f;
    float loy = -1.0f + iy * 0.125f, hiy = loy + 0.125f;
    float loz = -1.0f + iz * 0.125f, hiz = loz + 0.125f;
    u16* lst = wl[w];
    int nl = 0;
    for (int bs = 0; bs < ns; bs += 64) {
        int s = bs + lane;
        bool pass = false;
        if (s < ns) {
            float4 a = sA[s];
            float dx = a.x - fminf(fmaxf(a.x, lox), hix);
            float dy = a.y - fminf(fmaxf(a.y, loy), hiy);
            float dz = a.z - fminf(fmaxf(a.z, loz), hiz);
            float d2 = fmaf(dx, dx, fmaf(dy, dy, dz * dz));
            float rr = fmaf(-0.2f, a.w, 0.201f);   // r + 0.101
            pass = d2 <= rr * rr;
        }
        u64 m = __ballot(pass);
        if (pass) lst[nl + __popcll(m & ((1ull << lane) - 1ull))] = (u16)s;
        nl += __popcll(m);
    }

    float TA = 1.0f, dA = 0.0f, rA = 0.0f, gA = 0.0f, bA = 0.0f;
    float TB = 1.0f, dB = 0.0f, rB = 0.0f, gB = 0.0f, bB = 0.0f;

#define BLEND(AV, BV) { \
    float dxA = xA - AV.x, dyA = yA - AV.y, dzA = zA - AV.z; \
    float d2A = fmaf(dxA, dxA, fmaf(dyA, dyA, dzA * dzA)); \
    float omtA = __builtin_amdgcn_fmed3f( \
        fmaf(5.0f, __builtin_amdgcn_sqrtf(d2A), AV.w), 0.0f, 1.0f); \
    float TnA = omtA * TA; float tTA = TA - TnA; \
    dA = fmaf(tTA, BV.x, dA); rA = fmaf(tTA, BV.y, rA); \
    gA = fmaf(tTA, BV.z, gA); bA = fmaf(tTA, BV.w, bA); TA = TnA; \
    float dxB = xB - AV.x, dyB = yB - AV.y, dzB = zB - AV.z; \
    float d2B = fmaf(dxB, dxB, fmaf(dyB, dyB, dzB * dzB)); \
    float omtB = __builtin_amdgcn_fmed3f( \
        fmaf(5.0f, __builtin_amdgcn_sqrtf(d2B), AV.w), 0.0f, 1.0f); \
    float TnB = omtB * TB; float tTB = TB - TnB; \
    dB = fmaf(tTB, BV.x, dB); rB = fmaf(tTB, BV.y, rB); \
    gB = fmaf(tTB, BV.z, gB); bB = fmaf(tTB, BV.w, bB); TB = TnB; }

    if (nl > 0) {
        int jb = (((nl + 63) >> 6) << 6) - 64;
        int myId = lst[min(jb + lane, nl - 1)];
        for (; jb >= 0; jb -= 64) {
            int hi = nl - jb; hi = hi > 64 ? 64 : hi;
            int nextMy = (jb >= 64) ? (int)lst[jb - 64 + lane] : 0;
            int c = hi - 1;
            // 3-stage preload (depth-2 pipeline, zero-move rotation)
            int s0 = __builtin_amdgcn_readlane(myId, c);
            float4 A0 = sA[s0], B0 = sB[s0];
            int s1 = __builtin_amdgcn_readlane(myId, c >= 1 ? c - 1 : 0);
            float4 A1 = sA[s1], B1 = sB[s1];
            int s2 = __builtin_amdgcn_readlane(myId, c >= 2 ? c - 2 : 0);
            float4 A2 = sA[s2], B2 = sB[s2];
            while (c >= 3) {
                BLEND(A0, B0);
                { int sp = __builtin_amdgcn_readlane(myId, c - 3);
                  A0 = sA[sp]; B0 = sB[sp]; }
                BLEND(A1, B1);
                { int sp = __builtin_amdgcn_readlane(myId, c >= 4 ? c - 4 : 0);
                  A1 = sA[sp]; B1 = sB[sp]; }
                BLEND(A2, B2);
                { int sp = __builtin_amdgcn_readlane(myId, c >= 5 ? c - 5 : 0);
                  A2 = sA[sp]; B2 = sB[sp]; }
                c -= 3;
            }
            if (c >= 0) BLEND(A0, B0);
            if (c >= 1) BLEND(A1, B1);
            if (c >= 2) BLEND(A2, B2);
            myId = nextMy;
        }
    }
#undef BLEND

    float* rgb = out + n;
    if (vA) {
        float inv = 1.0f / (1.0f + 1e-6f - TA);
        out[iA] = dA;
        rgb[3 * iA]     = fminf(fmaxf(rA * inv, 0.0f), 1.0f);
        rgb[3 * iA + 1] = fminf(fmaxf(gA * inv, 0.0f), 1.0f);
        rgb[3 * iA + 2] = fminf(fmaxf(bA * inv, 0.0f), 1.0f);
    }
    if (vB) {
        float inv = 1.0f / (1.0f + 1e-6f - TB);
        out[iB] = dB;
        rgb[3 * iB]     = fminf(fmaxf(rB * inv, 0.0f), 1.0f);
        rgb[3 * iB + 1] = fminf(fmaxf(gB * inv, 0.0f), 1.0f);
        rgb[3 * iB + 2] = fminf(fmaxf(bB * inv, 0.0f), 1.0f);
    }
}

// ---- Fallback: R4 direct kernel ----
#define PTS 4
__global__ __launch_bounds__(256) void stroke_direct(
    const float* __restrict__ coords, const float* __restrict__ shape,
    const float* __restrict__ color, const float* __restrict__ alpha,
    float* __restrict__ out, int n, int ns)
{
    __shared__ float4 fA[MAXS + 1];
    __shared__ float4 fB[MAXS + 1];
    for (int s = threadIdx.x; s < ns; s += blockDim.x) {
        float4 sp = ((const float4*)shape)[s];
        fA[s + 1] = make_float4(sp.x, sp.y, sp.z, fmaf(-5.0f, sp.w, 0.5f));
        fB[s + 1] = make_float4(fmaxf(alpha[s], 0.0f) * 50.0f,
                                color[3 * s], color[3 * s + 1], color[3 * s + 2]);
    }
    __syncthreads();
    const int base = blockIdx.x * (blockDim.x * PTS) + threadIdx.x;
    float cx[PTS], cy[PTS], cz[PTS], T[PTS], Ad[PTS], Ar[PTS], Ag[PTS], Ab[PTS];
#pragma unroll
    for (int k = 0; k < PTS; ++k) {
        int i = base + k * 256; i = (i < n) ? i : (n - 1);
        contract_pt(coords[3 * i], coords[3 * i + 1], coords[3 * i + 2],
                    cx[k], cy[k], cz[k]);
        T[k] = 1.0f; Ad[k] = Ar[k] = Ag[k] = Ab[k] = 0.0f;
    }
    float4 a = fA[ns], b = fB[ns];
#pragma unroll 2
    for (int s = ns - 1; s >= 0; --s) {
        float4 an = fA[s], bn = fB[s];
#pragma unroll
        for (int k = 0; k < PTS; ++k) {
            float dx = cx[k] - a.x, dy = cy[k] - a.y, dz = cz[k] - a.z;
            float d2 = fmaf(dx, dx, fmaf(dy, dy, dz * dz));
            float dist = __builtin_amdgcn_sqrtf(d2);
            float omt = fminf(fmaxf(fmaf(5.0f, dist, a.w), 0.0f), 1.0f);
            float Tn = omt * T[k];
            float tT = T[k] - Tn;
            Ad[k] = fmaf(tT, b.x, Ad[k]); Ar[k] = fmaf(tT, b.y, Ar[k]);
            Ag[k] = fmaf(tT, b.z, Ag[k]); Ab[k] = fmaf(tT, b.w, Ab[k]);
            T[k] = Tn;
        }
        a = an; b = bn;
    }
    float* rgb = out + n;
    float* cw  = out + 4 * (size_t)n;
#pragma unroll
    for (int k = 0; k < PTS; ++k) {
        int i = base + k * 256;
        if (i >= n) break;
        float inv = 1.0f / (1.0f + 1e-6f - T[k]);
        out[i] = Ad[k];
        rgb[3 * i]     = fminf(fmaxf(Ar[k] * inv, 0.0f), 1.0f);
        rgb[3 * i + 1] = fminf(fmaxf(Ag[k] * inv, 0.0f), 1.0f);
        rgb[3 * i + 2] = fminf(fmaxf(Ab[k] * inv, 0.0f), 1.0f);
        cw[3 * i]     = cx[k];
        cw[3 * i + 1] = cy[k];
        cw[3 * i + 2] = cz[k];
    }
}

extern "C" void kernel_launch(void* const* d_in, const int* in_sizes, int n_in,
                              void* d_out, int out_size, void* d_ws, size_t ws_size,
                              hipStream_t stream) {
    const float* coords = (const float*)d_in[0];
    const float* shape  = (const float*)d_in[1];
    const float* color  = (const float*)d_in[2];
    const float* alpha  = (const float*)d_in[3];
    float* out = (float*)d_out;

    int n  = in_sizes[0] / 3;
    int ns = in_sizes[1] / 4;

    auto al = [](size_t v) { return (v + 255) & ~(size_t)255; };

    int nbA = (n + 2047) / 2048;
    int maxChunks = (n + CHK - 1) / CHK + 64 * 65;
    size_t slotCap = (size_t)n + 64 * 64 * CHK;

    size_t o_superCnt   = 0;                       // 256
    size_t o_superBase  = 256;                     // 256
    size_t o_superCur   = 512;                     // 256
    size_t o_superSlotB = 768;                     // 256
    size_t o_superChB   = 1024;                    // 256
    size_t o_superCntB  = al(1280);                // nbA*256
    size_t o_chunk      = al(o_superCntB + (size_t)nbA * 256);
    size_t o_key        = al(o_chunk + (size_t)maxChunks * 8);
    size_t o_pts        = al(o_key + (size_t)n);
    size_t need         = o_pts + slotCap * 16;

    if (ws_size >= need && ns <= MAXS && n >= 1 && n <= (1 << 21)) {
        char* w = (char*)d_ws;
        int*    superCnt  = (int*)(w + o_superCnt);
        int*    superBase = (int*)(w + o_superBase);
        int*    superCur  = (int*)(w + o_superCur);
        int*    superSlotB= (int*)(w + o_superSlotB);
        int*    superChB  = (int*)(w + o_superChB);
        int*    superCntB = (int*)(w + o_superCntB);
        int2*   chunkInfo = (int2*)(w + o_chunk);
        u8*     keyArr    = (u8*)(w + o_key);
        float4* sortedPts = (float4*)(w + o_pts);
        float4* sortedTmp = (float4*)out;          // aliases density+rgb

        kA<<<nbA, 256, 0, stream>>>(coords, out, superCntB, n);
        kB<<<1, 256, 0, stream>>>(superCntB, nbA, superCnt, superBase,
                                  superCur, superSlotB, superChB);
        kC<<<nbA, 256, 0, stream>>>(out, superCur, sortedTmp, keyArr, n);
        kD<<<512, 1024, 0, stream>>>(superCnt, superBase, superSlotB, superChB,
                                     sortedTmp, keyArr, sortedPts, chunkInfo,
                                     maxChunks);
        kF<<<(maxChunks + 3) / 4, 256, 0, stream>>>(
            shape, color, alpha, chunkInfo, sortedPts, out, n, ns, maxChunks);
    } else {
        int per_block = 256 * PTS;
        int grid = (n + per_block - 1) / per_block;
        stroke_direct<<<grid, 256, 0, stream>>>(coords, shape, color, alpha, out, n, ns);
    }
}